// Round 1
// baseline (345.904 us; speedup 1.0000x reference)
//
#include <hip/hip_runtime.h>

// Flip to 0 if absmax fails large: selects legacy (non-partitionable) JAX threefry stream.
#define JAX_THREEFRY_PARTITIONABLE 1

namespace {

constexpr int BN   = 2;      // batch
constexpr int C0   = 64;
constexpr int HH   = 100;
constexpr int WWW  = 100;
constexpr int LL   = 10000;  // H*W
constexpr int TL   = 20000;  // 2L
constexpr int CHK  = 144;
constexpr int NCHK = 139;    // (TL+16)/144
constexpr int NPAD = 16;
constexpr int WINR = 432;    // 3*144

// ws layout in float slots
constexpr int OFF_ROT  = 0;                   // rotT [4][64][16]
constexpr int OFF_WT1  = OFF_ROT + 4096;      // [64*9][16]
constexpr int OFF_WT2  = OFF_WT1 + 9216;      // [16*9][16]
constexpr int OFF_WTS  = OFF_WT2 + 2304;      // [64][16]
constexpr int OFF_HT   = OFF_WTS + 1024;      // h_tmp [4][16][10000]
constexpr int OFF_F    = OFF_HT + 640000;     // F [2][20000][16]
constexpr int OFF_SC   = OFF_F + 640000;      // SC [2][136]: E00,E01,E10,E11, rA[64], rB[64]
constexpr int OFF_AB   = OFF_SC + 272;        // AB [2][20000][2]
constexpr int OFF_CODE = OFF_AB + 80000;      // codes u8 [8][20000] (40000 float slots)
constexpr int OFF_RANK = OFF_CODE + 40000;    // rank int [8][20000]
constexpr int OFF_N0   = OFF_RANK + 160000;   // n0 int [8][139]
constexpr int OFF_INV  = OFF_N0 + 1112;       // inv int [10000]

__device__ __forceinline__ unsigned rotl32(unsigned v, int r) {
  return (v << r) | (v >> (32 - r));
}

// JAX threefry2x32, 20 rounds, key injection every 4.
__device__ void tf2x32(unsigned k0, unsigned k1, unsigned x0, unsigned x1,
                       unsigned& o0, unsigned& o1) {
  unsigned ks2 = k0 ^ k1 ^ 0x1BD11BDAu;
  x0 += k0; x1 += k1;
#define TFR(r) { x0 += x1; x1 = rotl32(x1, r); x1 ^= x0; }
  TFR(13) TFR(15) TFR(26) TFR(6)  x0 += k1;  x1 += ks2 + 1u;
  TFR(17) TFR(29) TFR(16) TFR(24) x0 += ks2; x1 += k0 + 2u;
  TFR(13) TFR(15) TFR(26) TFR(6)  x0 += k0;  x1 += k1 + 3u;
  TFR(17) TFR(29) TFR(16) TFR(24) x0 += k1;  x1 += ks2 + 4u;
  TFR(13) TFR(15) TFR(26) TFR(6)  x0 += ks2; x1 += k0 + 5u;
#undef TFR
  o0 = x0; o1 = x1;
}

// XLA's ErfInv32 polynomial (math.cc), no fp contraction to match XLA rounding.
__device__ float xla_erfinv(float x) {
#pragma clang fp contract(off)
  float w = -log1pf(-x * x);
  float p;
  if (w < 5.0f) {
    w = w - 2.5f;
    p = 2.81022636e-08f;
    p = 3.43273939e-07f  + p * w;
    p = -3.5233877e-06f  + p * w;
    p = -4.39150654e-06f + p * w;
    p = 0.00021858087f   + p * w;
    p = -0.00125372503f  + p * w;
    p = -0.00417768164f  + p * w;
    p = 0.246640727f     + p * w;
    p = 1.50140941f      + p * w;
  } else {
    w = sqrtf(w) - 3.0f;
    p = -0.000200214257f;
    p = 0.000100950558f + p * w;
    p = 0.00134934322f  + p * w;
    p = -0.00367342844f + p * w;
    p = 0.00573950773f  + p * w;
    p = -0.0076224613f  + p * w;
    p = 0.00943887047f  + p * w;
    p = 1.00167406f     + p * w;
    p = 2.83297682f     + p * w;
  }
  return p * x;
}

// rot = jax.random.normal(key(42), (16,4,64)); store transposed rotT[h][j][c].
__global__ void k_rot(float* __restrict__ rotT) {
  int i = blockIdx.x * 256 + threadIdx.x;
  if (i >= 4096) return;
  unsigned o0, o1, bits;
#if JAX_THREEFRY_PARTITIONABLE
  tf2x32(0u, 42u, 0u, (unsigned)i, o0, o1);
  bits = o0 ^ o1;
#else
  if (i < 2048) { tf2x32(0u, 42u, (unsigned)i, (unsigned)(i + 2048), o0, o1); bits = o0; }
  else          { tf2x32(0u, 42u, (unsigned)(i - 2048), (unsigned)i, o0, o1); bits = o1; }
#endif
  unsigned fb = (bits >> 9) | 0x3f800000u;
  float f = __uint_as_float(fb) - 1.0f;
  const float lo = __uint_as_float(0xBF7FFFFFu);  // nextafter(-1,0)
  float u = fmaxf(lo, f * 2.0f + lo);             // (hi-lo) rounds to exactly 2.0f
  float r = __uint_as_float(0x3FB504F3u) * xla_erfinv(u);  // sqrt(2) in f32
  int c = i >> 8, h = (i >> 6) & 3, j = i & 63;   // rot[c][h][j] row-major flat
  rotT[(h * 64 + j) * 16 + c] = r;
}

// transpose m-block weights for 16-consecutive-co access
__global__ void k_wt(const float* __restrict__ mw1, const float* __restrict__ mw2,
                     const float* __restrict__ mws,
                     float* __restrict__ wT1, float* __restrict__ wT2,
                     float* __restrict__ wTs) {
  int i = blockIdx.x * 256 + threadIdx.x;
  if (i < 9216) { int o = i / 576; int r = i % 576; wT1[r * 16 + o] = mw1[i]; }
  if (i < 2304) { int o = i / 144; int r = i % 144; wT2[r * 16 + o] = mw2[i]; }
  if (i < 1024) { int o = i / 64;  int ci = i % 64; wTs[ci * 16 + o] = mws[i]; }
}

// m-block conv1: 64->16 3x3 + bias + relu, on n = src*2+b (src: 0=fd1, 1=fd2)
__global__ __launch_bounds__(256) void k_conv1(
    const float* __restrict__ fd1, const float* __restrict__ fd2,
    const float* __restrict__ wT1, const float* __restrict__ mb1,
    float* __restrict__ ht) {
  int blk = blockIdx.x;
  int n = blk / 49, tile = blk % 49;
  int ty0 = (tile / 7) * 16, tx0 = (tile % 7) * 16;
  const float* in = ((n >> 1) ? fd2 : fd1) + (n & 1) * (C0 * LL);
  int tid = threadIdx.x;
  int tx = tid & 15, ty = tid >> 4;
  int y = ty0 + ty, x = tx0 + tx;
  bool inb = (y < HH) && (x < WWW);
  __shared__ float sIn[16][18][18];
  float acc[16];
#pragma unroll
  for (int c = 0; c < 16; ++c) acc[c] = 0.f;
  for (int cc = 0; cc < 4; ++cc) {
    for (int idx = tid; idx < 16 * 18 * 18; idx += 256) {
      int ci = idx / 324, r = idx % 324, iy = r / 18, ix = r % 18;
      int gy = ty0 - 1 + iy, gx = tx0 - 1 + ix;
      float v = 0.f;
      if (gy >= 0 && gy < HH && gx >= 0 && gx < WWW)
        v = in[(cc * 16 + ci) * LL + gy * WWW + gx];
      sIn[ci][iy][ix] = v;
    }
    __syncthreads();
    if (inb) {
#pragma unroll
      for (int ci = 0; ci < 16; ++ci)
#pragma unroll
        for (int t = 0; t < 9; ++t) {
          float v = sIn[ci][ty + t / 3][tx + t % 3];
          const float* wp = wT1 + ((cc * 16 + ci) * 9 + t) * 16;
#pragma unroll
          for (int co = 0; co < 16; ++co) acc[co] = fmaf(v, wp[co], acc[co]);
        }
    }
    __syncthreads();
  }
  if (inb) {
#pragma unroll
    for (int co = 0; co < 16; ++co)
      ht[(n * 16 + co) * LL + y * WWW + x] = fmaxf(acc[co] + mb1[co], 0.f);
  }
}

// m-block conv2 (16->16 3x3 + b2) + skip (1x1 64->16 + mbs); write F[b][src*L+t][16]
__global__ __launch_bounds__(256) void k_conv2(
    const float* __restrict__ fd1, const float* __restrict__ fd2,
    const float* __restrict__ ht, const float* __restrict__ wT2,
    const float* __restrict__ mb2, const float* __restrict__ wTs,
    const float* __restrict__ mbs, float* __restrict__ F) {
  int blk = blockIdx.x;
  int n = blk / 49, tile = blk % 49;
  int ty0 = (tile / 7) * 16, tx0 = (tile % 7) * 16;
  int src = n >> 1, b = n & 1;
  const float* in = (src ? fd2 : fd1) + b * (C0 * LL);
  const float* hbase = ht + n * 16 * LL;
  int tid = threadIdx.x;
  int tx = tid & 15, ty = tid >> 4;
  int y = ty0 + ty, x = tx0 + tx;
  bool inb = (y < HH) && (x < WWW);
  __shared__ float sH[16][18][18];
  for (int idx = tid; idx < 16 * 18 * 18; idx += 256) {
    int ci = idx / 324, r = idx % 324, iy = r / 18, ix = r % 18;
    int gy = ty0 - 1 + iy, gx = tx0 - 1 + ix;
    float v = 0.f;
    if (gy >= 0 && gy < HH && gx >= 0 && gx < WWW) v = hbase[ci * LL + gy * WWW + gx];
    sH[ci][iy][ix] = v;
  }
  __syncthreads();
  if (!inb) return;
  float acc[16];
#pragma unroll
  for (int co = 0; co < 16; ++co) acc[co] = mb2[co] + mbs[co];
#pragma unroll
  for (int ci = 0; ci < 16; ++ci)
#pragma unroll
    for (int t = 0; t < 9; ++t) {
      float v = sH[ci][ty + t / 3][tx + t % 3];
      const float* wp = wT2 + (ci * 9 + t) * 16;
#pragma unroll
      for (int co = 0; co < 16; ++co) acc[co] = fmaf(v, wp[co], acc[co]);
    }
  for (int ci = 0; ci < 64; ++ci) {
    float v = in[ci * LL + y * WWW + x];
    const float* wp = wTs + ci * 16;
#pragma unroll
    for (int co = 0; co < 16; ++co) acc[co] = fmaf(v, wp[co], acc[co]);
  }
  float* Fr = F + ((b * TL) + src * LL + y * WWW + x) * 16;
#pragma unroll
  for (int co = 0; co < 16; ++co) Fr[co] = acc[co];
}

// codes in permuted order: code[bh][t'] = argmax over [rv, -rv] at row ri[t']
__global__ __launch_bounds__(256) void k_codes(
    const float* __restrict__ F, const float* __restrict__ rotT,
    const int* __restrict__ ri, unsigned char* __restrict__ codes) {
  int bh = blockIdx.y;
  int b = bh >> 2, h = bh & 3;
  __shared__ float srot[1024];
  int tid = threadIdx.x;
  for (int i = tid; i < 1024; i += 256) srot[i] = rotT[h * 1024 + i];
  __syncthreads();
  int t = blockIdx.x * 256 + tid;
  if (t >= TL) return;
  int pos = ri[t];
  const float* Fr = F + (b * TL + pos) * 16;
  float q[16];
#pragma unroll
  for (int c = 0; c < 16; ++c) q[c] = Fr[c];
  float best = -1e30f; int bi = 0;
  float worst = 1e30f; int wi = 0;
  for (int j = 0; j < 64; ++j) {
    float v = 0.f;
    const float* rp = srot + j * 16;
#pragma unroll
    for (int c = 0; c < 16; ++c) v = fmaf(q[c], rp[c], v);
    if (v > best)  { best = v;  bi = j; }
    if (v < worst) { worst = v; wi = j; }
  }
  // argmax over [rv(0..63), -rv(64..127)], first occurrence wins ties
  int code = (best >= -worst) ? bi : (64 + wi);
  codes[bh * TL + t] = (unsigned char)code;
}

// stable counting sort per (b,h); emit rank_of[t'] and even-parity chunk counts n0
__global__ __launch_bounds__(256) void k_sort(
    const unsigned char* __restrict__ codes,
    int* __restrict__ rank_of, int* __restrict__ n0g) {
  int bh = blockIdx.x;
  const unsigned char* keys = codes + bh * TL;
  __shared__ unsigned short cnt[240][128];  // per-segment counts -> offsets (in place)
  __shared__ unsigned int totals[128];
  __shared__ unsigned int baseoff[128];
  __shared__ unsigned int n0s[NCHK];
  int tid = threadIdx.x;
  for (int i = tid; i < 240 * 128 / 2; i += 256) ((unsigned int*)cnt)[i] = 0u;
  for (int i = tid; i < NCHK; i += 256) n0s[i] = 0u;
  __syncthreads();
  const int SEG = 84;  // 240*84 = 20160 >= 20000
  int base = tid * SEG;
  int nloc = (tid < 240) ? (TL - base) : 0;
  if (nloc > SEG) nloc = SEG;
  if (nloc < 0) nloc = 0;
  for (int e = 0; e < nloc; ++e) cnt[tid][keys[base + e]]++;
  __syncthreads();
  if (tid < 128) {
    unsigned int s = 0;
    for (int g = 0; g < 240; ++g) s += cnt[g][tid];
    totals[tid] = s;
  }
  __syncthreads();
  if (tid == 0) {
    unsigned int run = 0;
    for (int c = 0; c < 128; ++c) { baseoff[c] = run; run += totals[c]; }
  }
  __syncthreads();
  if (tid < 128) {
    unsigned int run = baseoff[tid];
    for (int g = 0; g < 240; ++g) {
      unsigned int v = cnt[g][tid];
      cnt[g][tid] = (unsigned short)run;
      run += v;
    }
  }
  __syncthreads();
  for (int e = 0; e < nloc; ++e) {
    int idx = base + e;
    int c = keys[idx];
    int r = cnt[tid][c]++;
    rank_of[bh * TL + idx] = r;
    if (!(idx & 1)) {  // parity-0 (even t') row
      atomicAdd(&n0s[r / CHK], 1u);
      if (r >= TL - NPAD) atomicAdd(&n0s[NCHK - 1], 1u);  // padding duplicates last 16 ranks
    }
  }
  __syncthreads();
  for (int i = tid; i < NCHK; i += 256) n0g[bh * NCHK + i] = (int)n0s[i];
}

// per-batch scalars: E[si][col] = exp(q_si . k_col) * z_col
__global__ void k_scal(const float* __restrict__ F, const int* __restrict__ ri,
                       float* __restrict__ SC) {
#pragma clang fp contract(off)
  int b = threadIdx.x;
  if (b >= BN) return;
  int j0 = ri[0], jL = ri[LL];
  const float* qA = F + (b * TL + j0) * 16;
  const float* qB = F + (b * TL + jL) * 16;
  float nA = 0.f, nB = 0.f;
  for (int c = 0; c < 16; ++c) { nA += qA[c] * qA[c]; nB += qB[c] * qB[c]; }
  float mA = fmaxf(sqrtf(nA), 5e-5f), mB = fmaxf(sqrtf(nB), 5e-5f);
  float d00 = 0.f, d01 = 0.f, d10 = 0.f, d11 = 0.f;
  for (int c = 0; c < 16; ++c) {
    float kAc = qA[c] / mA, kBc = qB[c] / mB;
    d00 += qA[c] * kAc; d01 += qA[c] * kBc;
    d10 += qB[c] * kAc; d11 += qB[c] * kBc;
  }
  float zA = (j0 < LL) ? 0.01f : 0.99f;
  float zB = (jL < LL) ? 0.01f : 0.99f;
  float* sc = SC + b * 136;
  sc[0] = expf(d00) * zA; sc[1] = expf(d01) * zB;
  sc[2] = expf(d10) * zA; sc[3] = expf(d11) * zB;
}

// rA/rB: one output pixel of the aux (a1, input fd1) or ref (a2) resblock
__global__ __launch_bounds__(576) void k_point(
    const float* __restrict__ fd1, const float* __restrict__ refin,
    const int* __restrict__ ri,
    const float* __restrict__ a1w1, const float* __restrict__ a1b1,
    const float* __restrict__ a1w2, const float* __restrict__ a1b2,
    const float* __restrict__ a2w1, const float* __restrict__ a2b1,
    const float* __restrict__ a2w2, const float* __restrict__ a2b2,
    float* __restrict__ SC) {
  int b = blockIdx.x & 1, which = blockIdx.x >> 1;
  int pos = ri[which * LL];
  const float *in, *w1, *b1, *w2, *b2;
  int sp;
  if (pos < LL) { in = fd1 + b * C0 * LL; w1 = a1w1; b1 = a1b1; w2 = a1w2; b2 = a1b2; sp = pos; }
  else { in = refin + b * C0 * LL; w1 = a2w1; b1 = a2b1; w2 = a2w2; b2 = a2b2; sp = pos - LL; }
  int y = sp / WWW, x = sp % WWW;
  __shared__ float hh[9][64];
  int tid = threadIdx.x;
  int p = tid / 64, ch = tid % 64;
  {
    int yy = y + p / 3 - 1, xx = x + p % 3 - 1;
    float a = 0.f;
    if (yy >= 0 && yy < HH && xx >= 0 && xx < WWW) {
      a = b1[ch];
      for (int ci = 0; ci < 64; ++ci) {
        const float* wrow = w1 + (ch * 64 + ci) * 9;
#pragma unroll
        for (int t = 0; t < 9; ++t) {
          int gy = yy + t / 3 - 1, gx = xx + t % 3 - 1;
          if (gy >= 0 && gy < HH && gx >= 0 && gx < WWW)
            a = fmaf(in[ci * LL + gy * WWW + gx], wrow[t], a);
        }
      }
      a = fmaxf(a, 0.f);
    }
    hh[p][ch] = a;
  }
  __syncthreads();
  if (tid < 64) {
    int co = tid;
    float a = in[co * LL + y * WWW + x] + b2[co];  // skip = x (no ws), + conv2 bias
    for (int ci = 0; ci < 64; ++ci) {
      const float* wrow = w2 + (co * 64 + ci) * 9;
#pragma unroll
      for (int t = 0; t < 9; ++t) a = fmaf(hh[t][ci], wrow[t], a);
    }
    SC[b * 136 + 4 + which * 64 + co] = a;
  }
}

__global__ void k_inv(const int* __restrict__ ri, int* __restrict__ inv) {
  int t = blockIdx.x * 256 + threadIdx.x;
  if (t >= TL) return;
  int p = ri[t];
  if (p < LL) inv[p] = t;
}

// per (b, t'): alpha/beta = hash-summed numerators over hash-summed denominators
__global__ void k_ab(const int* __restrict__ rank_of, const int* __restrict__ n0,
                     const float* __restrict__ SC, float* __restrict__ AB) {
  int gid = blockIdx.x * 256 + threadIdx.x;
  if (gid >= BN * TL) return;
  int b = gid / TL, t = gid % TL;
  int si = t & 1;
  float e0 = SC[b * 136 + si * 2 + 0];
  float e1 = SC[b * 136 + si * 2 + 1];
  float s0 = 0.f, s1 = 0.f;
  for (int h = 0; h < 4; ++h) {
    int r = rank_of[(b * 4 + h) * TL + t];
    int k = r / CHK;
    int km = (k == 0) ? NCHK - 1 : k - 1;
    int kp = (k == NCHK - 1) ? 0 : k + 1;
    const int* nb = n0 + (b * 4 + h) * NCHK;
    int W0 = nb[k] + nb[km] + nb[kp];
    s0 += (float)W0 * e0;
    s1 += (float)(WINR - W0) * e1;
  }
  float invd = 1.f / (s0 + s1);
  AB[(b * TL + t) * 2 + 0] = s0 * invd;
  AB[(b * TL + t) * 2 + 1] = s1 * invd;
}

// out[b][c][p] = alpha*rA[c] + beta*rB[c], p < L
__global__ __launch_bounds__(256) void k_out(
    const int* __restrict__ inv, const float* __restrict__ AB,
    const float* __restrict__ SC, float* __restrict__ out) {
  int b = blockIdx.y;
  int p = blockIdx.x * 256 + threadIdx.x;
  if (p >= LL) return;
  int t = inv[p];
  float al = AB[(b * TL + t) * 2 + 0];
  float be = AB[(b * TL + t) * 2 + 1];
  const float* rA = SC + b * 136 + 4;
  const float* rB = rA + 64;
  float* o = out + b * C0 * LL + p;
#pragma unroll
  for (int c = 0; c < 64; ++c) o[c * LL] = al * rA[c] + be * rB[c];
}

}  // namespace

extern "C" void kernel_launch(void* const* d_in, const int* in_sizes, int n_in,
                              void* d_out, int out_size, void* d_ws, size_t ws_size,
                              hipStream_t stream) {
  const float* fd1  = (const float*)d_in[0];
  const float* fd2  = (const float*)d_in[1];
  const float* reff = (const float*)d_in[2];
  const int*   ri   = (const int*)d_in[3];
  const float* mw1  = (const float*)d_in[4];
  const float* mb1  = (const float*)d_in[5];
  const float* mw2  = (const float*)d_in[6];
  const float* mb2  = (const float*)d_in[7];
  const float* mws  = (const float*)d_in[8];
  const float* mbs  = (const float*)d_in[9];
  const float* a1w1 = (const float*)d_in[10];
  const float* a1b1 = (const float*)d_in[11];
  const float* a1w2 = (const float*)d_in[12];
  const float* a1b2 = (const float*)d_in[13];
  const float* a2w1 = (const float*)d_in[14];
  const float* a2b1 = (const float*)d_in[15];
  const float* a2w2 = (const float*)d_in[16];
  const float* a2b2 = (const float*)d_in[17];

  float* ws = (float*)d_ws;
  float* rotT = ws + OFF_ROT;
  float* wT1  = ws + OFF_WT1;
  float* wT2  = ws + OFF_WT2;
  float* wTs  = ws + OFF_WTS;
  float* ht   = ws + OFF_HT;
  float* F    = ws + OFF_F;
  float* SC   = ws + OFF_SC;
  float* AB   = ws + OFF_AB;
  unsigned char* codes = (unsigned char*)(ws + OFF_CODE);
  int* rank_of = (int*)(ws + OFF_RANK);
  int* n0      = (int*)(ws + OFF_N0);
  int* invp    = (int*)(ws + OFF_INV);

  k_rot<<<dim3(16), dim3(256), 0, stream>>>(rotT);
  k_wt<<<dim3(36), dim3(256), 0, stream>>>(mw1, mw2, mws, wT1, wT2, wTs);
  k_conv1<<<dim3(196), dim3(256), 0, stream>>>(fd1, fd2, wT1, mb1, ht);
  k_conv2<<<dim3(196), dim3(256), 0, stream>>>(fd1, fd2, ht, wT2, mb2, wTs, mbs, F);
  k_codes<<<dim3(79, 8), dim3(256), 0, stream>>>(F, rotT, ri, codes);
  k_sort<<<dim3(8), dim3(256), 0, stream>>>(codes, rank_of, n0);
  k_scal<<<dim3(1), dim3(64), 0, stream>>>(F, ri, SC);
  k_point<<<dim3(4), dim3(576), 0, stream>>>(fd1, reff, ri, a1w1, a1b1, a1w2, a1b2,
                                             a2w1, a2b1, a2w2, a2b2, SC);
  k_inv<<<dim3(79), dim3(256), 0, stream>>>(ri, invp);
  k_ab<<<dim3(157), dim3(256), 0, stream>>>(rank_of, n0, SC, AB);
  k_out<<<dim3(40, 2), dim3(256), 0, stream>>>(invp, AB, SC, (float*)d_out);
}

// Round 2
// 197.209 us; speedup vs baseline: 1.7540x; 1.7540x over previous
//
#include <hip/hip_runtime.h>

// Flip to 0 if absmax fails large: selects legacy (non-partitionable) JAX threefry stream.
#define JAX_THREEFRY_PARTITIONABLE 1

namespace {

constexpr int BN   = 2;      // batch
constexpr int C0   = 64;
constexpr int HH   = 100;
constexpr int WWW  = 100;
constexpr int LL   = 10000;  // H*W
constexpr int TL   = 20000;  // 2L
constexpr int CHK  = 144;
constexpr int NCHK = 139;    // (TL+16)/144
constexpr int NPAD = 16;
constexpr int WINR = 432;    // 3*144

// ws layout in float slots
constexpr int OFF_ROT  = 0;                   // rotT [4][64][16]
constexpr int OFF_WT1  = OFF_ROT + 4096;      // [64*9][16]
constexpr int OFF_WT2  = OFF_WT1 + 9216;      // [16*9][16]
constexpr int OFF_WTS  = OFF_WT2 + 2304;      // [64][16]
constexpr int OFF_HT   = OFF_WTS + 1024;      // h_tmp [4][16][10000]
constexpr int OFF_F    = OFF_HT + 640000;     // F [2][20000][16]
constexpr int OFF_SC   = OFF_F + 640000;      // SC [2][136]: E00,E01,E10,E11, rA[64], rB[64]
constexpr int OFF_AB   = OFF_SC + 272;        // AB [2][20000][2]
constexpr int OFF_CODE = OFF_AB + 80000;      // codes u8 [8][20000] (40000 float slots)
constexpr int OFF_RANK = OFF_CODE + 40000;    // rank int [8][20000]
constexpr int OFF_N0   = OFF_RANK + 160000;   // n0 int [8][139]
constexpr int OFF_INV  = OFF_N0 + 1112;       // inv int [10000]
constexpr int OFF_AUX  = OFF_INV + 10000;     // auxT: [a1w1T|a1w2T|a2w1T|a2w2T], each [576][64]

constexpr int AUXW = 36864;  // 64*64*9

__device__ __forceinline__ unsigned rotl32(unsigned v, int r) {
  return (v << r) | (v >> (32 - r));
}

// JAX threefry2x32, 20 rounds, key injection every 4.
__device__ void tf2x32(unsigned k0, unsigned k1, unsigned x0, unsigned x1,
                       unsigned& o0, unsigned& o1) {
  unsigned ks2 = k0 ^ k1 ^ 0x1BD11BDAu;
  x0 += k0; x1 += k1;
#define TFR(r) { x0 += x1; x1 = rotl32(x1, r); x1 ^= x0; }
  TFR(13) TFR(15) TFR(26) TFR(6)  x0 += k1;  x1 += ks2 + 1u;
  TFR(17) TFR(29) TFR(16) TFR(24) x0 += ks2; x1 += k0 + 2u;
  TFR(13) TFR(15) TFR(26) TFR(6)  x0 += k0;  x1 += k1 + 3u;
  TFR(17) TFR(29) TFR(16) TFR(24) x0 += k1;  x1 += ks2 + 4u;
  TFR(13) TFR(15) TFR(26) TFR(6)  x0 += ks2; x1 += k0 + 5u;
#undef TFR
  o0 = x0; o1 = x1;
}

// XLA's ErfInv32 polynomial (math.cc), no fp contraction to match XLA rounding.
__device__ float xla_erfinv(float x) {
#pragma clang fp contract(off)
  float w = -log1pf(-x * x);
  float p;
  if (w < 5.0f) {
    w = w - 2.5f;
    p = 2.81022636e-08f;
    p = 3.43273939e-07f  + p * w;
    p = -3.5233877e-06f  + p * w;
    p = -4.39150654e-06f + p * w;
    p = 0.00021858087f   + p * w;
    p = -0.00125372503f  + p * w;
    p = -0.00417768164f  + p * w;
    p = 0.246640727f     + p * w;
    p = 1.50140941f      + p * w;
  } else {
    w = sqrtf(w) - 3.0f;
    p = -0.000200214257f;
    p = 0.000100950558f + p * w;
    p = 0.00134934322f  + p * w;
    p = -0.00367342844f + p * w;
    p = 0.00573950773f  + p * w;
    p = -0.0076224613f  + p * w;
    p = 0.00943887047f  + p * w;
    p = 1.00167406f     + p * w;
    p = 2.83297682f     + p * w;
  }
  return p * x;
}

// Merged prep: aux weight transposes + rot RNG + m-weight transposes + inv perm.
// work: [0,147456) auxT | [147456,151552) rot | [151552,160768) wT | [160768,180768) inv
__global__ void k_prep(const float* __restrict__ mw1, const float* __restrict__ mw2,
                       const float* __restrict__ mws,
                       const float* __restrict__ a1w1, const float* __restrict__ a1w2,
                       const float* __restrict__ a2w1, const float* __restrict__ a2w2,
                       const int* __restrict__ ri,
                       float* __restrict__ rotT, float* __restrict__ wT1,
                       float* __restrict__ wT2, float* __restrict__ wTs,
                       float* __restrict__ auxT, int* __restrict__ inv) {
  int gid = blockIdx.x * 256 + threadIdx.x;
  if (gid < 4 * AUXW) {
    int wsel = gid / AUXW, j = gid % AUXW;
    const float* src = (wsel == 0) ? a1w1 : (wsel == 1) ? a1w2 : (wsel == 2) ? a2w1 : a2w2;
    int co = j / 576, r = j % 576;                 // coalesced read
    auxT[wsel * AUXW + r * 64 + co] = src[j];
    return;
  }
  int g2 = gid - 4 * AUXW;
  if (g2 < 4096) {
    int i = g2;
    unsigned o0, o1, bits;
#if JAX_THREEFRY_PARTITIONABLE
    tf2x32(0u, 42u, 0u, (unsigned)i, o0, o1);
    bits = o0 ^ o1;
#else
    if (i < 2048) { tf2x32(0u, 42u, (unsigned)i, (unsigned)(i + 2048), o0, o1); bits = o0; }
    else          { tf2x32(0u, 42u, (unsigned)(i - 2048), (unsigned)i, o0, o1); bits = o1; }
#endif
    unsigned fb = (bits >> 9) | 0x3f800000u;
    float f = __uint_as_float(fb) - 1.0f;
    const float lo = __uint_as_float(0xBF7FFFFFu);  // nextafter(-1,0)
    float u = fmaxf(lo, f * 2.0f + lo);
    float r = __uint_as_float(0x3FB504F3u) * xla_erfinv(u);  // sqrt(2)*erfinv(u)
    int c = i >> 8, h = (i >> 6) & 3, j = i & 63;
    rotT[(h * 64 + j) * 16 + c] = r;
    return;
  }
  int g3 = g2 - 4096;
  if (g3 < 9216) {
    { int o = g3 / 576; int r = g3 % 576; wT1[r * 16 + o] = mw1[g3]; }
    if (g3 < 2304) { int o = g3 / 144; int r = g3 % 144; wT2[r * 16 + o] = mw2[g3]; }
    if (g3 < 1024) { int o = g3 / 64;  int ci = g3 % 64; wTs[ci * 16 + o] = mws[g3]; }
    return;
  }
  int g4 = g3 - 9216;
  if (g4 < TL) {
    int p = ri[g4];
    if (p < LL) inv[p] = g4;
  }
}

// m-block conv1: 64->16 3x3 + bias + relu, on n = src*2+b (src: 0=fd1, 1=fd2)
__global__ __launch_bounds__(256) void k_conv1(
    const float* __restrict__ fd1, const float* __restrict__ fd2,
    const float* __restrict__ wT1, const float* __restrict__ mb1,
    float* __restrict__ ht) {
  int blk = blockIdx.x;
  int n = blk / 49, tile = blk % 49;
  int ty0 = (tile / 7) * 16, tx0 = (tile % 7) * 16;
  const float* in = ((n >> 1) ? fd2 : fd1) + (n & 1) * (C0 * LL);
  int tid = threadIdx.x;
  int tx = tid & 15, ty = tid >> 4;
  int y = ty0 + ty, x = tx0 + tx;
  bool inb = (y < HH) && (x < WWW);
  __shared__ float sIn[16][18][18];
  float acc[16];
#pragma unroll
  for (int c = 0; c < 16; ++c) acc[c] = 0.f;
  for (int cc = 0; cc < 4; ++cc) {
    for (int idx = tid; idx < 16 * 18 * 18; idx += 256) {
      int ci = idx / 324, r = idx % 324, iy = r / 18, ix = r % 18;
      int gy = ty0 - 1 + iy, gx = tx0 - 1 + ix;
      float v = 0.f;
      if (gy >= 0 && gy < HH && gx >= 0 && gx < WWW)
        v = in[(cc * 16 + ci) * LL + gy * WWW + gx];
      sIn[ci][iy][ix] = v;
    }
    __syncthreads();
    if (inb) {
#pragma unroll
      for (int ci = 0; ci < 16; ++ci)
#pragma unroll
        for (int t = 0; t < 9; ++t) {
          float v = sIn[ci][ty + t / 3][tx + t % 3];
          const float* wp = wT1 + ((cc * 16 + ci) * 9 + t) * 16;
#pragma unroll
          for (int co = 0; co < 16; ++co) acc[co] = fmaf(v, wp[co], acc[co]);
        }
    }
    __syncthreads();
  }
  if (inb) {
#pragma unroll
    for (int co = 0; co < 16; ++co)
      ht[(n * 16 + co) * LL + y * WWW + x] = fmaxf(acc[co] + mb1[co], 0.f);
  }
}

// m-block conv2 (16->16 3x3 + b2) + skip (1x1 64->16 + mbs); write F[b][src*L+t][16]
__global__ __launch_bounds__(256) void k_conv2(
    const float* __restrict__ fd1, const float* __restrict__ fd2,
    const float* __restrict__ ht, const float* __restrict__ wT2,
    const float* __restrict__ mb2, const float* __restrict__ wTs,
    const float* __restrict__ mbs, float* __restrict__ F) {
  int blk = blockIdx.x;
  int n = blk / 49, tile = blk % 49;
  int ty0 = (tile / 7) * 16, tx0 = (tile % 7) * 16;
  int src = n >> 1, b = n & 1;
  const float* in = (src ? fd2 : fd1) + b * (C0 * LL);
  const float* hbase = ht + n * 16 * LL;
  int tid = threadIdx.x;
  int tx = tid & 15, ty = tid >> 4;
  int y = ty0 + ty, x = tx0 + tx;
  bool inb = (y < HH) && (x < WWW);
  __shared__ float sH[16][18][18];
  for (int idx = tid; idx < 16 * 18 * 18; idx += 256) {
    int ci = idx / 324, r = idx % 324, iy = r / 18, ix = r % 18;
    int gy = ty0 - 1 + iy, gx = tx0 - 1 + ix;
    float v = 0.f;
    if (gy >= 0 && gy < HH && gx >= 0 && gx < WWW) v = hbase[ci * LL + gy * WWW + gx];
    sH[ci][iy][ix] = v;
  }
  __syncthreads();
  if (!inb) return;
  float acc[16];
#pragma unroll
  for (int co = 0; co < 16; ++co) acc[co] = mb2[co] + mbs[co];
#pragma unroll
  for (int ci = 0; ci < 16; ++ci)
#pragma unroll
    for (int t = 0; t < 9; ++t) {
      float v = sH[ci][ty + t / 3][tx + t % 3];
      const float* wp = wT2 + (ci * 9 + t) * 16;
#pragma unroll
      for (int co = 0; co < 16; ++co) acc[co] = fmaf(v, wp[co], acc[co]);
    }
  for (int ci = 0; ci < 64; ++ci) {
    float v = in[ci * LL + y * WWW + x];
    const float* wp = wTs + ci * 16;
#pragma unroll
    for (int co = 0; co < 16; ++co) acc[co] = fmaf(v, wp[co], acc[co]);
  }
  float* Fr = F + ((b * TL) + src * LL + y * WWW + x) * 16;
#pragma unroll
  for (int co = 0; co < 16; ++co) Fr[co] = acc[co];
}

// codes in permuted order: code[bh][t'] = argmax over [rv, -rv] at row ri[t']
__global__ __launch_bounds__(256) void k_codes(
    const float* __restrict__ F, const float* __restrict__ rotT,
    const int* __restrict__ ri, unsigned char* __restrict__ codes) {
  int bh = blockIdx.y;
  int b = bh >> 2, h = bh & 3;
  __shared__ float srot[1024];
  int tid = threadIdx.x;
  for (int i = tid; i < 1024; i += 256) srot[i] = rotT[h * 1024 + i];
  __syncthreads();
  int t = blockIdx.x * 256 + tid;
  if (t >= TL) return;
  int pos = ri[t];
  const float* Fr = F + (b * TL + pos) * 16;
  float q[16];
#pragma unroll
  for (int c = 0; c < 16; ++c) q[c] = Fr[c];
  float best = -1e30f; int bi = 0;
  float worst = 1e30f; int wi = 0;
  for (int j = 0; j < 64; ++j) {
    float v = 0.f;
    const float* rp = srot + j * 16;
#pragma unroll
    for (int c = 0; c < 16; ++c) v = fmaf(q[c], rp[c], v);
    if (v > best)  { best = v;  bi = j; }
    if (v < worst) { worst = v; wi = j; }
  }
  int code = (best >= -worst) ? bi : (64 + wi);
  codes[bh * TL + t] = (unsigned char)code;
}

// stable counting sort per (b,h); emit rank_of[t'] and even-parity chunk counts n0
__global__ __launch_bounds__(256) void k_sort(
    const unsigned char* __restrict__ codes,
    int* __restrict__ rank_of, int* __restrict__ n0g) {
  int bh = blockIdx.x;
  const unsigned char* keys = codes + bh * TL;
  __shared__ unsigned short cnt[240][128];
  __shared__ unsigned int totals[128];
  __shared__ unsigned int baseoff[128];
  __shared__ unsigned int n0s[NCHK];
  int tid = threadIdx.x;
  for (int i = tid; i < 240 * 128 / 2; i += 256) ((unsigned int*)cnt)[i] = 0u;
  for (int i = tid; i < NCHK; i += 256) n0s[i] = 0u;
  __syncthreads();
  const int SEG = 84;
  int base = tid * SEG;
  int nloc = (tid < 240) ? (TL - base) : 0;
  if (nloc > SEG) nloc = SEG;
  if (nloc < 0) nloc = 0;
  for (int e = 0; e < nloc; ++e) cnt[tid][keys[base + e]]++;
  __syncthreads();
  if (tid < 128) {
    unsigned int s = 0;
    for (int g = 0; g < 240; ++g) s += cnt[g][tid];
    totals[tid] = s;
  }
  __syncthreads();
  if (tid == 0) {
    unsigned int run = 0;
    for (int c = 0; c < 128; ++c) { baseoff[c] = run; run += totals[c]; }
  }
  __syncthreads();
  if (tid < 128) {
    unsigned int run = baseoff[tid];
    for (int g = 0; g < 240; ++g) {
      unsigned int v = cnt[g][tid];
      cnt[g][tid] = (unsigned short)run;
      run += v;
    }
  }
  __syncthreads();
  for (int e = 0; e < nloc; ++e) {
    int idx = base + e;
    int c = keys[idx];
    int r = cnt[tid][c]++;
    rank_of[bh * TL + idx] = r;
    if (!(idx & 1)) {
      atomicAdd(&n0s[r / CHK], 1u);
      if (r >= TL - NPAD) atomicAdd(&n0s[NCHK - 1], 1u);
    }
  }
  __syncthreads();
  for (int i = tid; i < NCHK; i += 256) n0g[bh * NCHK + i] = (int)n0s[i];
}

// blocks 0..3: rA/rB point-resblock, LDS-staged; block 4: per-batch E scalars.
__global__ __launch_bounds__(576) void k_point(
    const float* __restrict__ fd1, const float* __restrict__ refin,
    const int* __restrict__ ri, const float* __restrict__ auxT,
    const float* __restrict__ a1b1, const float* __restrict__ a1b2,
    const float* __restrict__ a2b1, const float* __restrict__ a2b2,
    const float* __restrict__ F, float* __restrict__ SC) {
  int tid = threadIdx.x;
  if (blockIdx.x == 4) {
    // k_scal path
#pragma clang fp contract(off)
    int b = tid;
    if (b >= BN) return;
    int j0 = ri[0], jL = ri[LL];
    const float* qA = F + (b * TL + j0) * 16;
    const float* qB = F + (b * TL + jL) * 16;
    float nA = 0.f, nB = 0.f;
    for (int c = 0; c < 16; ++c) { nA += qA[c] * qA[c]; nB += qB[c] * qB[c]; }
    float mA = fmaxf(sqrtf(nA), 5e-5f), mB = fmaxf(sqrtf(nB), 5e-5f);
    float d00 = 0.f, d01 = 0.f, d10 = 0.f, d11 = 0.f;
    for (int c = 0; c < 16; ++c) {
      float kAc = qA[c] / mA, kBc = qB[c] / mB;
      d00 += qA[c] * kAc; d01 += qA[c] * kBc;
      d10 += qB[c] * kAc; d11 += qB[c] * kBc;
    }
    float zA = (j0 < LL) ? 0.01f : 0.99f;
    float zB = (jL < LL) ? 0.01f : 0.99f;
    float* sc = SC + b * 136;
    sc[0] = expf(d00) * zA; sc[1] = expf(d01) * zB;
    sc[2] = expf(d10) * zA; sc[3] = expf(d11) * zB;
    return;
  }
  int b = blockIdx.x & 1, which = blockIdx.x >> 1;
  int pos = ri[which * LL];
  const float *in, *w1T, *b1, *w2T, *b2;
  int sp;
  if (pos < LL) {
    in = fd1 + b * C0 * LL; w1T = auxT; b1 = a1b1; w2T = auxT + AUXW; b2 = a1b2; sp = pos;
  } else {
    in = refin + b * C0 * LL; w1T = auxT + 2 * AUXW; b1 = a2b1; w2T = auxT + 3 * AUXW;
    b2 = a2b2; sp = pos - LL;
  }
  int y = sp / WWW, x = sp % WWW;

  __shared__ float sPatch[64][25];   // 5x5 input patch, all 64 ci
  __shared__ float sW[144 * 64];     // 16-ci weight chunk, [ci_l*9+t][co]
  __shared__ float sH[9][64];        // conv1 output (relu'd)
  __shared__ float sPart[9][64];     // conv2 tap partials

  // stage patch (zero-padded)
  for (int idx = tid; idx < 64 * 25; idx += 576) {
    int ci = idx / 25, pp = idx % 25;
    int gy = y - 2 + pp / 5, gx = x - 2 + pp % 5;
    float v = 0.f;
    if (gy >= 0 && gy < HH && gx >= 0 && gx < WWW) v = in[ci * LL + gy * WWW + gx];
    sPatch[ci][pp] = v;
  }

  int p = tid / 64, ch = tid & 63;   // p in 0..8
  int p3 = p / 3, pm = p % 3;
  int yy = y + p3 - 1, xx = x + pm - 1;
  bool inb = (yy >= 0) && (yy < HH) && (xx >= 0) && (xx < WWW);

  float acc0 = 0.f, acc1 = 0.f;
  for (int cc = 0; cc < 4; ++cc) {
    __syncthreads();  // patch ready (cc=0) / sW reuse safe (cc>0)
    for (int i = tid; i < 144 * 64; i += 576) sW[i] = w1T[cc * 9216 + i];
    __syncthreads();
    if (inb) {
#pragma unroll
      for (int ci = 0; ci < 16; ++ci) {
        const float* wp = &sW[ci * 9 * 64 + ch];
        const float* pr = &sPatch[cc * 16 + ci][0];
#pragma unroll
        for (int t = 0; t < 9; ++t) {
          float v = pr[(p3 + t / 3) * 5 + (pm + t % 3)];
          if (ci & 1) acc1 = fmaf(v, wp[t * 64], acc1);
          else        acc0 = fmaf(v, wp[t * 64], acc0);
        }
      }
    }
  }
  sH[p][ch] = inb ? fmaxf(acc0 + acc1 + b1[ch], 0.f) : 0.f;
  __syncthreads();

  // conv2: tap group g = p handles tap t=g; 64 coalesced weight loads from L2
  {
    float part = 0.f;
    const float* wbase = w2T + p * 64 + ch;  // (ci*9+p)*64 + ch
    for (int ci = 0; ci < 64; ++ci) part = fmaf(sH[p][ci], wbase[ci * 9 * 64], part);
    sPart[p][ch] = part;
  }
  __syncthreads();
  if (tid < 64) {
    int co = tid;
    float a = in[co * LL + y * WWW + x] + b2[co];  // skip (no ws) + conv2 bias
#pragma unroll
    for (int g = 0; g < 9; ++g) a += sPart[g][co];
    SC[b * 136 + 4 + which * 64 + co] = a;
  }
}

// per (b, t'): alpha/beta = hash-summed numerators over hash-summed denominators
__global__ void k_ab(const int* __restrict__ rank_of, const int* __restrict__ n0,
                     const float* __restrict__ SC, float* __restrict__ AB) {
  int gid = blockIdx.x * 256 + threadIdx.x;
  if (gid >= BN * TL) return;
  int b = gid / TL, t = gid % TL;
  int si = t & 1;
  float e0 = SC[b * 136 + si * 2 + 0];
  float e1 = SC[b * 136 + si * 2 + 1];
  float s0 = 0.f, s1 = 0.f;
  for (int h = 0; h < 4; ++h) {
    int r = rank_of[(b * 4 + h) * TL + t];
    int k = r / CHK;
    int km = (k == 0) ? NCHK - 1 : k - 1;
    int kp = (k == NCHK - 1) ? 0 : k + 1;
    const int* nb = n0 + (b * 4 + h) * NCHK;
    int W0 = nb[k] + nb[km] + nb[kp];
    s0 += (float)W0 * e0;
    s1 += (float)(WINR - W0) * e1;
  }
  float invd = 1.f / (s0 + s1);
  AB[(b * TL + t) * 2 + 0] = s0 * invd;
  AB[(b * TL + t) * 2 + 1] = s1 * invd;
}

// out[b][c][p] = alpha*rA[c] + beta*rB[c], p < L
__global__ __launch_bounds__(256) void k_out(
    const int* __restrict__ inv, const float* __restrict__ AB,
    const float* __restrict__ SC, float* __restrict__ out) {
  int b = blockIdx.y;
  int p = blockIdx.x * 256 + threadIdx.x;
  if (p >= LL) return;
  int t = inv[p];
  float al = AB[(b * TL + t) * 2 + 0];
  float be = AB[(b * TL + t) * 2 + 1];
  const float* rA = SC + b * 136 + 4;
  const float* rB = rA + 64;
  float* o = out + b * C0 * LL + p;
#pragma unroll
  for (int c = 0; c < 64; ++c) o[c * LL] = al * rA[c] + be * rB[c];
}

}  // namespace

extern "C" void kernel_launch(void* const* d_in, const int* in_sizes, int n_in,
                              void* d_out, int out_size, void* d_ws, size_t ws_size,
                              hipStream_t stream) {
  const float* fd1  = (const float*)d_in[0];
  const float* fd2  = (const float*)d_in[1];
  const float* reff = (const float*)d_in[2];
  const int*   ri   = (const int*)d_in[3];
  const float* mw1  = (const float*)d_in[4];
  const float* mb1  = (const float*)d_in[5];
  const float* mw2  = (const float*)d_in[6];
  const float* mb2  = (const float*)d_in[7];
  const float* mws  = (const float*)d_in[8];
  const float* mbs  = (const float*)d_in[9];
  const float* a1w1 = (const float*)d_in[10];
  const float* a1b1 = (const float*)d_in[11];
  const float* a1w2 = (const float*)d_in[12];
  const float* a1b2 = (const float*)d_in[13];
  const float* a2w1 = (const float*)d_in[14];
  const float* a2b1 = (const float*)d_in[15];
  const float* a2w2 = (const float*)d_in[16];
  const float* a2b2 = (const float*)d_in[17];

  float* ws = (float*)d_ws;
  float* rotT = ws + OFF_ROT;
  float* wT1  = ws + OFF_WT1;
  float* wT2  = ws + OFF_WT2;
  float* wTs  = ws + OFF_WTS;
  float* ht   = ws + OFF_HT;
  float* F    = ws + OFF_F;
  float* SC   = ws + OFF_SC;
  float* AB   = ws + OFF_AB;
  unsigned char* codes = (unsigned char*)(ws + OFF_CODE);
  int* rank_of = (int*)(ws + OFF_RANK);
  int* n0      = (int*)(ws + OFF_N0);
  int* invp    = (int*)(ws + OFF_INV);
  float* auxT  = ws + OFF_AUX;

  // k_prep total work = 4*36864 + 4096 + 9216 + 20000 = 180768
  k_prep<<<dim3(707), dim3(256), 0, stream>>>(mw1, mw2, mws, a1w1, a1w2, a2w1, a2w2,
                                              ri, rotT, wT1, wT2, wTs, auxT, invp);
  k_conv1<<<dim3(196), dim3(256), 0, stream>>>(fd1, fd2, wT1, mb1, ht);
  k_conv2<<<dim3(196), dim3(256), 0, stream>>>(fd1, fd2, ht, wT2, mb2, wTs, mbs, F);
  k_codes<<<dim3(79, 8), dim3(256), 0, stream>>>(F, rotT, ri, codes);
  k_sort<<<dim3(8), dim3(256), 0, stream>>>(codes, rank_of, n0);
  k_point<<<dim3(5), dim3(576), 0, stream>>>(fd1, reff, ri, auxT, a1b1, a1b2,
                                             a2b1, a2b2, F, SC);
  k_ab<<<dim3(157), dim3(256), 0, stream>>>(rank_of, n0, SC, AB);
  k_out<<<dim3(40, 2), dim3(256), 0, stream>>>(invp, AB, SC, (float*)d_out);
}